// Round 1
// 649.185 us; speedup vs baseline: 1.0325x; 1.0325x over previous
//
#include <hip/hip_runtime.h>

// Problem constants: B=N=256, D=S=1024
// out = [ctx 256*1024 fp32 ; W 256*256*1024 fp32]

typedef _Float16 half8 __attribute__((ext_vector_type(8)));
typedef float floatx16 __attribute__((ext_vector_type(16)));

static __device__ __forceinline__ void split_f32(float x, _Float16& hi, _Float16& lo) {
    _Float16 h = (_Float16)x;
    hi = h;
    lo = (_Float16)(x - (float)h);
}

// ---------------------------------------------------------------------------
// Small GEMM: C[M,N] = A[M,K] @ B, fp32 in, hi/lo fp16 split on BOTH operands
// (3 MFMAs) for near-fp32 accuracy. BT=true: B stored [N,K] (contract fast dim,
// direct staging). BT=false: B stored [K,N] (transpose staging).
// OUT_HILO=false -> write fp32 C. OUT_HILO=true -> write hi/lo fp16 pair.
// Tile 64x64, 256 threads (4 waves as 2x2 of 32x32), BK=32.
// ---------------------------------------------------------------------------
template <bool BT, bool OUT_HILO>
__global__ __launch_bounds__(256, 2) void gemm_small(
    const float* __restrict__ Ag, const float* __restrict__ Bg,
    float* __restrict__ Cf, _Float16* __restrict__ Chi, _Float16* __restrict__ Clo,
    int Kdim, int Ndim)
{
    __shared__ __align__(16) _Float16 AsHi[4 * 64 * 8];
    __shared__ __align__(16) _Float16 AsLo[4 * 64 * 8];
    __shared__ __align__(16) _Float16 BsHi[4 * 64 * 8];
    __shared__ __align__(16) _Float16 BsLo[4 * 64 * 8];

    const int tid  = threadIdx.x;
    const int lane = tid & 63;
    const int wave = tid >> 6;
    const int wy = wave >> 1, wx = wave & 1;
    const int l31 = lane & 31, l5 = lane >> 5;
    const int m0 = blockIdx.y * 64, n0 = blockIdx.x * 64;

    floatx16 acc;
#pragma unroll
    for (int j = 0; j < 16; ++j) acc[j] = 0.0f;

    const int sA_m  = tid >> 2;  // 0..63 (row for A / row-of-B for BT)
    const int sA_kg = tid & 3;   // 0..3
    const int sB_n  = tid & 63;  // NN staging: n (coalesced)
    const int sB_kg = tid >> 6;  // NN staging: kg

    const int nkt = Kdim / 32;
#pragma unroll 1
    for (int kt = 0; kt < nkt; ++kt) {
        __syncthreads();
        {   // stage A chunk [32k x 64m] -> [kg][m][8] hi/lo
            const float* src = Ag + (size_t)(m0 + sA_m) * Kdim + kt * 32 + sA_kg * 8;
            half8 hi, lo;
#pragma unroll
            for (int j = 0; j < 8; ++j) {
                _Float16 h, l;
                split_f32(src[j], h, l);
                hi[j] = h; lo[j] = l;
            }
            *(half8*)&AsHi[(sA_kg * 64 + sA_m) * 8] = hi;
            *(half8*)&AsLo[(sA_kg * 64 + sA_m) * 8] = lo;
        }
        if constexpr (BT) {
            const float* src = Bg + (size_t)(n0 + sA_m) * Kdim + kt * 32 + sA_kg * 8;
            half8 hi, lo;
#pragma unroll
            for (int j = 0; j < 8; ++j) {
                _Float16 h, l;
                split_f32(src[j], h, l);
                hi[j] = h; lo[j] = l;
            }
            *(half8*)&BsHi[(sA_kg * 64 + sA_m) * 8] = hi;
            *(half8*)&BsLo[(sA_kg * 64 + sA_m) * 8] = lo;
        } else {
            const float* src = Bg + (size_t)(kt * 32 + sB_kg * 8) * Ndim + n0 + sB_n;
            half8 hi, lo;
#pragma unroll
            for (int j = 0; j < 8; ++j) {
                _Float16 h, l;
                split_f32(src[(size_t)j * Ndim], h, l);
                hi[j] = h; lo[j] = l;
            }
            *(half8*)&BsHi[(sB_kg * 64 + sB_n) * 8] = hi;
            *(half8*)&BsLo[(sB_kg * 64 + sB_n) * 8] = lo;
        }
        __syncthreads();
#pragma unroll
        for (int ks = 0; ks < 2; ++ks) {
            const int kg = ks * 2 + l5;
            const half8 ah = *(half8*)&AsHi[(kg * 64 + wy * 32 + l31) * 8];
            const half8 al = *(half8*)&AsLo[(kg * 64 + wy * 32 + l31) * 8];
            const half8 bh = *(half8*)&BsHi[(kg * 64 + wx * 32 + l31) * 8];
            const half8 bl = *(half8*)&BsLo[(kg * 64 + wx * 32 + l31) * 8];
            acc = __builtin_amdgcn_mfma_f32_32x32x16_f16(ah, bh, acc, 0, 0, 0);
            acc = __builtin_amdgcn_mfma_f32_32x32x16_f16(ah, bl, acc, 0, 0, 0);
            acc = __builtin_amdgcn_mfma_f32_32x32x16_f16(al, bh, acc, 0, 0, 0);
        }
    }

    // C/D layout (verified): col = lane&31, row = (reg&3) + 8*(reg>>2) + 4*(lane>>5)
#pragma unroll
    for (int reg = 0; reg < 16; ++reg) {
        const int row = m0 + wy * 32 + (reg & 3) + 8 * (reg >> 2) + 4 * l5;
        const int col = n0 + wx * 32 + l31;
        const float v = acc[reg];
        if constexpr (OUT_HILO) {
            _Float16 h, l;
            split_f32(v, h, l);
            Chi[(size_t)row * Ndim + col] = h;
            Clo[(size_t)row * Ndim + col] = l;
        } else {
            Cf[(size_t)row * Ndim + col] = v;
        }
    }
}

// ---------------------------------------------------------------------------
// Fused: per (i, b-tile of 64): logits = (Mhi+Mlo) @ fp16(FV[i])  (2 MFMAs),
// row softmax over d=1024, write W, accumulate ctx[i,d] += W * FV[i,b,d].
// 512 threads = 8 waves (wy in {0,1} m-half, wx in {0..3} d-slice of 256).
// K=256 in 16 chunks of 16; register prefetch overlaps global load w/ compute.
//
// XCD-aware swizzle (T1): the 4 bt-blocks of each i all stage the SAME 1 MB
// FV[i]; default round-robin dispatch puts them on 4 DIFFERENT XCDs (private
// L2s) -> each fetched FV[i] from HBM (measured 2.4x read over-fetch). Remap
// so same-i blocks land on the same XCD within Dw<=24: the 2nd..4th L2-hit.
// Grid is 1D 1024; hardware XCD = ordinal & 7 (8 XCDs, 1024 % 8 == 0).
// ---------------------------------------------------------------------------
__global__ __launch_bounds__(512, 2) void fused_attn(
    const float* __restrict__ FV, const _Float16* __restrict__ Mhi,
    const _Float16* __restrict__ Mlo, float* __restrict__ ctx,
    float* __restrict__ Wout)
{
    __shared__ __align__(16) _Float16 AsHi[2 * 64 * 8];
    __shared__ __align__(16) _Float16 AsLo[2 * 64 * 8];
    __shared__ __align__(16) _Float16 Bs[2 * 1024 * 8];
    __shared__ __align__(16) float red1[64 * 4];
    __shared__ __align__(16) float red2[64 * 4];

    const int tid  = threadIdx.x;
    const int lane = tid & 63;
    const int wave = tid >> 6;
    const int wx = wave & 3;   // d-slice (256 cols)
    const int wy = wave >> 2;  // m-half (32 rows)
    const int l31 = lane & 31, l5 = lane >> 5;

    // XCD-aware swizzle: ordinal w -> (i, bt) such that all 4 bt of an i
    // share one XCD, and per-XCD instantaneous footprint is 16 i * 64 KB
    // chunk ~ 1 MB (fits 4 MB L2).
    const int w   = blockIdx.x;   // 0..1023
    const int xcd = w & 7;
    const int k   = w >> 3;       // 0..127 (slot within XCD)
    const int i   = (xcd << 5) + (k >> 2);  // 0..255
    const int bt  = k & 3;                  // 0..3

    const float* __restrict__ FVi = FV + (size_t)i * 256 * 1024;

    floatx16 acc[8];
#pragma unroll
    for (int nt = 0; nt < 8; ++nt)
#pragma unroll
        for (int j = 0; j < 16; ++j) acc[nt][j] = 0.0f;

    const int am = tid >> 1, akg = tid & 1;  // A staging (tid < 128)

    // ---- prefetch chunk 0 into registers ----
    float pv[4][8];
    half8 pah, pal;
#pragma unroll
    for (int rep = 0; rep < 4; ++rep) {
        const int q8 = rep >> 1;
        const int d  = (rep & 1) * 512 + tid;
        const float* src = FVi + (size_t)(q8 * 8) * 1024 + d;
#pragma unroll
        for (int r = 0; r < 8; ++r) pv[rep][r] = src[(size_t)r * 1024];
    }
    if (tid < 128) {
        pah = *(const half8*)(Mhi + (size_t)(bt * 64 + am) * 256 + akg * 8);
        pal = *(const half8*)(Mlo + (size_t)(bt * 64 + am) * 256 + akg * 8);
    }

#pragma unroll 1
    for (int kt = 0; kt < 16; ++kt) {
        __syncthreads();  // drains prefetch (issued a full compute-phase ago)
        // ---- store staged chunk to LDS ----
        if (tid < 128) {
            *(half8*)&AsHi[(akg * 64 + am) * 8] = pah;
            *(half8*)&AsLo[(akg * 64 + am) * 8] = pal;
        }
#pragma unroll
        for (int rep = 0; rep < 4; ++rep) {
            const int q8 = rep >> 1;
            const int d  = (rep & 1) * 512 + tid;
            half8 h;
#pragma unroll
            for (int r = 0; r < 8; ++r) h[r] = (_Float16)pv[rep][r];
            *(half8*)&Bs[(q8 * 1024 + d) * 8] = h;
        }
        __syncthreads();
        // ---- prefetch next chunk (overlaps with compute below) ----
        if (kt + 1 < 16) {
#pragma unroll
            for (int rep = 0; rep < 4; ++rep) {
                const int q8 = rep >> 1;
                const int d  = (rep & 1) * 512 + tid;
                const float* src = FVi + (size_t)((kt + 1) * 16 + q8 * 8) * 1024 + d;
#pragma unroll
                for (int r = 0; r < 8; ++r) pv[rep][r] = src[(size_t)r * 1024];
            }
            if (tid < 128) {
                pah = *(const half8*)(Mhi + (size_t)(bt * 64 + am) * 256 + (kt + 1) * 16 + akg * 8);
                pal = *(const half8*)(Mlo + (size_t)(bt * 64 + am) * 256 + (kt + 1) * 16 + akg * 8);
            }
        }
        // ---- compute: 8 n-tiles x (hi,lo) MFMA ----
        const half8 ah = *(half8*)&AsHi[(l5 * 64 + wy * 32 + l31) * 8];
        const half8 al = *(half8*)&AsLo[(l5 * 64 + wy * 32 + l31) * 8];
#pragma unroll
        for (int nt = 0; nt < 8; ++nt) {
            const half8 b = *(half8*)&Bs[(l5 * 1024 + wx * 256 + nt * 32 + l31) * 8];
            acc[nt] = __builtin_amdgcn_mfma_f32_32x32x16_f16(ah, b, acc[nt], 0, 0, 0);
            acc[nt] = __builtin_amdgcn_mfma_f32_32x32x16_f16(al, b, acc[nt], 0, 0, 0);
        }
    }

    // ---- softmax over d (rows span 4 wx waves) ----
    // lane holds: col = wx*256 + nt*32 + l31 ; row = wy*32 + (reg&3)+8*(reg>>2)+4*l5
    float st[16];
#pragma unroll
    for (int reg = 0; reg < 16; ++reg) {
        float v = acc[0][reg];
#pragma unroll
        for (int nt = 1; nt < 8; ++nt) v = fmaxf(v, acc[nt][reg]);
#pragma unroll
        for (int off = 1; off < 32; off <<= 1) v = fmaxf(v, __shfl_xor(v, off));
        st[reg] = v;
    }
    if (l31 == 0) {
#pragma unroll
        for (int reg = 0; reg < 16; ++reg) {
            const int row = wy * 32 + (reg & 3) + 8 * (reg >> 2) + 4 * l5;
            red1[row * 4 + wx] = st[reg];
        }
    }
    __syncthreads();
    float rmax[16];
#pragma unroll
    for (int reg = 0; reg < 16; ++reg) {
        const int row = wy * 32 + (reg & 3) + 8 * (reg >> 2) + 4 * l5;
        const float4 m4 = *(const float4*)&red1[row * 4];
        rmax[reg] = fmaxf(fmaxf(m4.x, m4.y), fmaxf(m4.z, m4.w));
    }
#pragma unroll
    for (int reg = 0; reg < 16; ++reg) {
        float s = 0.0f;
#pragma unroll
        for (int nt = 0; nt < 8; ++nt) {
            const float p = __expf(acc[nt][reg] - rmax[reg]);
            acc[nt][reg] = p;
            s += p;
        }
#pragma unroll
        for (int off = 1; off < 32; off <<= 1) s += __shfl_xor(s, off);
        st[reg] = s;
    }
    if (l31 == 0) {
#pragma unroll
        for (int reg = 0; reg < 16; ++reg) {
            const int row = wy * 32 + (reg & 3) + 8 * (reg >> 2) + 4 * l5;
            red2[row * 4 + wx] = st[reg];
        }
    }
    __syncthreads();
    float inv[16];
#pragma unroll
    for (int reg = 0; reg < 16; ++reg) {
        const int row = wy * 32 + (reg & 3) + 8 * (reg >> 2) + 4 * l5;
        const float4 s4 = *(const float4*)&red2[row * 4];
        inv[reg] = 1.0f / (s4.x + s4.y + s4.z + s4.w);
    }

    // ---- write W, accumulate context ----
    float csum[8];
#pragma unroll
    for (int nt = 0; nt < 8; ++nt) csum[nt] = 0.0f;

    const int rowbase = bt * 64 + wy * 32;
#pragma unroll
    for (int nt = 0; nt < 8; ++nt) {
        const int col = wx * 256 + nt * 32 + l31;
#pragma unroll
        for (int reg = 0; reg < 16; ++reg) {
            const int row = (reg & 3) + 8 * (reg >> 2) + 4 * l5;
            const float w = acc[nt][reg] * inv[reg];
            Wout[((size_t)(i * 256 + rowbase + row)) * 1024 + col] = w;
            const float fv = FVi[(size_t)(rowbase + row) * 1024 + col];
            csum[nt] += w * fv;
        }
    }
#pragma unroll
    for (int nt = 0; nt < 8; ++nt) {
        const float v = csum[nt] + __shfl_xor(csum[nt], 32);
        if (l5 == 0)
            atomicAdd(&ctx[(size_t)i * 1024 + wx * 256 + nt * 32 + l31], v);
    }
}

// ---------------------------------------------------------------------------
extern "C" void kernel_launch(void* const* d_in, const int* in_sizes, int n_in,
                              void* d_out, int out_size, void* d_ws, size_t ws_size,
                              hipStream_t stream)
{
    const float* FV    = (const float*)d_in[0];  // [256,256,1024]
    const float* state = (const float*)d_in[1];  // [256,1024]
    const float* Q     = (const float*)d_in[2];  // [1024,1024]
    const float* Km    = (const float*)d_in[3];  // [1024,256]

    float* out = (float*)d_out;
    float* ctx = out;                 // [256,1024]
    float* W   = out + 256 * 1024;    // [256,256,1024]

    char* ws = (char*)d_ws;
    float*    A1  = (float*)ws;                                 // [256,1024] fp32, 1 MB
    _Float16* Mhi = (_Float16*)(ws + (1 << 20));                // [256,256] f16, 128 KB
    _Float16* Mlo = (_Float16*)(ws + (1 << 20) + (1 << 17));    // [256,256] f16, 128 KB

    // ctx accumulated with atomics -> zero it
    (void)hipMemsetAsync(ctx, 0, 256 * 1024 * sizeof(float), stream);

    // A1 = state @ Q^T   (B stored [N,K]: Q[s,t], contract t)
    gemm_small<true, false><<<dim3(16, 4), 256, 0, stream>>>(
        state, Q, A1, nullptr, nullptr, 1024, 1024);

    // M = A1 @ K  -> hi/lo fp16   (B stored [K,N])
    gemm_small<false, true><<<dim3(4, 4), 256, 0, stream>>>(
        A1, Km, nullptr, Mhi, Mlo, 1024, 256);

    // fused logits -> softmax -> W + ctx (XCD-swizzled 1D grid)
    fused_attn<<<dim3(1024), 512, 0, stream>>>(FV, Mhi, Mlo, ctx, W);
}